// Round 1
// baseline (388.097 us; speedup 1.0000x reference)
//
#include <hip/hip_runtime.h>

#define N_NODES 20000
#define N_EDGES 320000
#define IN_F    168
#define HID     256

// ---------------- graph prep ----------------

__global__ void edge_count_deg(const int* __restrict__ ei, const float* __restrict__ ew,
                               float* __restrict__ deg, int* __restrict__ counts) {
    int e = blockIdx.x * blockDim.x + threadIdx.x;
    if (e >= N_EDGES) return;
    int d = ei[N_EDGES + e];            // dst row of edge_index
    atomicAdd(&deg[d], ew[e]);
    atomicAdd(&counts[d], 1);
}

__global__ void finalize_dinv(float* __restrict__ deg) {
    int i = blockIdx.x * blockDim.x + threadIdx.x;
    if (i >= N_NODES) return;
    float d = deg[i] + 1.0f;            // self-loop weight 1.0
    deg[i] = rsqrtf(d);                 // deg >= 1 always
}

// single-block exclusive scan over counts -> offs (n+1 entries)
__global__ void scan_counts(const int* __restrict__ counts, int* __restrict__ offs, int n) {
    __shared__ int lds[1024];
    __shared__ int s_carry;
    if (threadIdx.x == 0) s_carry = 0;
    __syncthreads();
    for (int base = 0; base < n; base += 1024) {
        int i = base + (int)threadIdx.x;
        int v = (i < n) ? counts[i] : 0;
        lds[threadIdx.x] = v;
        __syncthreads();
        for (int off = 1; off < 1024; off <<= 1) {
            int t = (threadIdx.x >= (unsigned)off) ? lds[threadIdx.x - off] : 0;
            __syncthreads();
            lds[threadIdx.x] += t;
            __syncthreads();
        }
        int incl  = lds[threadIdx.x];
        int total = lds[1023];
        int c     = s_carry;
        __syncthreads();
        if (i < n) offs[i] = c + incl - v;
        if (threadIdx.x == 0) s_carry = c + total;
        __syncthreads();
    }
    if (threadIdx.x == 0) offs[n] = s_carry;
}

__global__ void scatter_edges(const int* __restrict__ ei, const float* __restrict__ ew,
                              const float* __restrict__ dinv, const int* __restrict__ offs,
                              int* __restrict__ cursor, int* __restrict__ csr_src,
                              float* __restrict__ csr_norm) {
    int e = blockIdx.x * blockDim.x + threadIdx.x;
    if (e >= N_EDGES) return;
    int s = ei[e];
    int d = ei[N_EDGES + e];
    int pos = offs[d] + atomicAdd(&cursor[d], 1);
    csr_src[pos]  = s;
    csr_norm[pos] = dinv[s] * ew[e] * dinv[d];
}

// ---------------- SGEMM: C[M,N] = A[M,K] * W[N,K]^T ----------------
// 64x64 tile, 256 threads, 4x4 microtile, BK=8 (168 and 256 both divisible by 8)

#define BM 64
#define BN 64
#define BK 8

__global__ __launch_bounds__(256) void sgemm_nt(const float* __restrict__ A,
                                                const float* __restrict__ W,
                                                float* __restrict__ C,
                                                int M, int N, int K) {
    __shared__ float As[BK][BM];
    __shared__ float Ws[BK][BN];
    int bm = blockIdx.x * BM;
    int bn = blockIdx.y * BN;
    int tid = threadIdx.x;
    int tx = tid & 15;       // 0..15 -> N
    int ty = tid >> 4;       // 0..15 -> M
    float acc[4][4] = {};

    for (int k0 = 0; k0 < K; k0 += BK) {
        // stage tiles: 512 floats each, 2 per thread
        int r  = tid >> 2;           // 0..63
        int kk = (tid & 3) * 2;      // 0,2,4,6
        int gm = bm + r;
        float a0 = 0.f, a1 = 0.f;
        if (gm < M) {
            a0 = A[gm * K + k0 + kk];
            a1 = A[gm * K + k0 + kk + 1];
        }
        As[kk][r]     = a0;
        As[kk + 1][r] = a1;
        int gn = bn + r;             // N == 256, grid covers exactly
        Ws[kk][r]     = W[gn * K + k0 + kk];
        Ws[kk + 1][r] = W[gn * K + k0 + kk + 1];
        __syncthreads();

        #pragma unroll
        for (int k = 0; k < BK; ++k) {
            float a[4], b[4];
            #pragma unroll
            for (int i = 0; i < 4; ++i) a[i] = As[k][ty * 4 + i];
            #pragma unroll
            for (int j = 0; j < 4; ++j) b[j] = Ws[k][tx * 4 + j];
            #pragma unroll
            for (int i = 0; i < 4; ++i)
                #pragma unroll
                for (int j = 0; j < 4; ++j)
                    acc[i][j] += a[i] * b[j];
        }
        __syncthreads();
    }

    #pragma unroll
    for (int i = 0; i < 4; ++i) {
        int gm = bm + ty * 4 + i;
        if (gm >= M) continue;
        #pragma unroll
        for (int j = 0; j < 4; ++j)
            C[gm * N + bn + tx * 4 + j] = acc[i][j];
    }
}

// ---------------- aggregation (+self-loop, +bias, ReLU) ----------------
// one block per dst node, one thread per feature

__global__ __launch_bounds__(256) void aggregate(const float* __restrict__ xw,
                                                 const float* __restrict__ dinv,
                                                 const int* __restrict__ offs,
                                                 const int* __restrict__ csr_src,
                                                 const float* __restrict__ csr_norm,
                                                 const float* __restrict__ bias,
                                                 float* __restrict__ out) {
    int n = blockIdx.x;
    int f = threadIdx.x;
    float di  = dinv[n];
    float acc = di * di * xw[n * HID + f];
    int p0 = offs[n], p1 = offs[n + 1];
    for (int p = p0; p < p1; ++p) {
        int   s = csr_src[p];
        float w = csr_norm[p];
        acc += w * xw[s * HID + f];
    }
    acc += bias[f];
    out[n * HID + f] = acc > 0.f ? acc : 0.f;
}

// ---------------- launch ----------------

extern "C" void kernel_launch(void* const* d_in, const int* in_sizes, int n_in,
                              void* d_out, int out_size, void* d_ws, size_t ws_size,
                              hipStream_t stream) {
    const float* x  = (const float*)d_in[0];
    const int*   ei = (const int*)d_in[1];
    const float* ew = (const float*)d_in[2];
    const float* W1 = (const float*)d_in[3];
    const float* b1 = (const float*)d_in[4];
    const float* W2 = (const float*)d_in[5];
    const float* b2 = (const float*)d_in[6];
    float* out = (float*)d_out;

    char* ws = (char*)d_ws;
    // layout (16B aligned sections)
    float* deg      = (float*)(ws);                         // 20000 f32  (becomes dinv)
    int*   counts   = (int*)(ws + 80000);                   // 20000 i32
    int*   cursor   = (int*)(ws + 160000);                  // 20000 i32
    int*   offs     = (int*)(ws + 240000);                  // 20001 i32 (pad to 80016)
    int*   csr_src  = (int*)(ws + 320016);                  // 320000 i32
    float* csr_norm = (float*)(ws + 1600016);               // 320000 f32
    float* xw       = (float*)(ws + 2880016);               // 20000x256 f32 (xw1, reused for xw2)
    float* h1       = (float*)(ws + 23360016);              // 20000x256 f32

    // zero deg/counts/cursor
    hipMemsetAsync(d_ws, 0, 240000, stream);

    const int TB = 256;
    edge_count_deg<<<(N_EDGES + TB - 1) / TB, TB, 0, stream>>>(ei, ew, deg, counts);
    finalize_dinv<<<(N_NODES + TB - 1) / TB, TB, 0, stream>>>(deg);
    scan_counts<<<1, 1024, 0, stream>>>(counts, offs, N_NODES);
    scatter_edges<<<(N_EDGES + TB - 1) / TB, TB, 0, stream>>>(ei, ew, deg, offs, cursor,
                                                              csr_src, csr_norm);

    dim3 g1((N_NODES + BM - 1) / BM, HID / BN);
    // layer 1
    sgemm_nt<<<g1, 256, 0, stream>>>(x, W1, xw, N_NODES, HID, IN_F);
    aggregate<<<N_NODES, HID, 0, stream>>>(xw, deg, offs, csr_src, csr_norm, b1, h1);
    // layer 2
    sgemm_nt<<<g1, 256, 0, stream>>>(h1, W2, xw, N_NODES, HID, HID);
    aggregate<<<N_NODES, HID, 0, stream>>>(xw, deg, offs, csr_src, csr_norm, b2, out);
}

// Round 2
// 348.914 us; speedup vs baseline: 1.1123x; 1.1123x over previous
//
#include <hip/hip_runtime.h>

#define N_NODES 20000
#define N_EDGES 320000
#define IN_F    168
#define HID     256

// ---------------- graph prep ----------------

__global__ void edge_count_deg(const int* __restrict__ ei, const float* __restrict__ ew,
                               float* __restrict__ deg, int* __restrict__ counts) {
    int e = blockIdx.x * blockDim.x + threadIdx.x;
    if (e >= N_EDGES) return;
    int d = ei[N_EDGES + e];            // dst row of edge_index
    atomicAdd(&deg[d], ew[e]);
    atomicAdd(&counts[d], 1);
}

__global__ void finalize_dinv(float* __restrict__ deg) {
    int i = blockIdx.x * blockDim.x + threadIdx.x;
    if (i >= N_NODES) return;
    float d = deg[i] + 1.0f;            // self-loop weight 1.0
    deg[i] = rsqrtf(d);                 // deg >= 1 always
}

// single-block exclusive scan over counts -> offs (n+1 entries)
__global__ void scan_counts(const int* __restrict__ counts, int* __restrict__ offs, int n) {
    __shared__ int lds[1024];
    __shared__ int s_carry;
    if (threadIdx.x == 0) s_carry = 0;
    __syncthreads();
    for (int base = 0; base < n; base += 1024) {
        int i = base + (int)threadIdx.x;
        int v = (i < n) ? counts[i] : 0;
        lds[threadIdx.x] = v;
        __syncthreads();
        for (int off = 1; off < 1024; off <<= 1) {
            int t = (threadIdx.x >= (unsigned)off) ? lds[threadIdx.x - off] : 0;
            __syncthreads();
            lds[threadIdx.x] += t;
            __syncthreads();
        }
        int incl  = lds[threadIdx.x];
        int total = lds[1023];
        int c     = s_carry;
        __syncthreads();
        if (i < n) offs[i] = c + incl - v;
        if (threadIdx.x == 0) s_carry = c + total;
        __syncthreads();
    }
    if (threadIdx.x == 0) offs[n] = s_carry;
}

__global__ void scatter_edges(const int* __restrict__ ei, const float* __restrict__ ew,
                              const float* __restrict__ dinv, const int* __restrict__ offs,
                              int* __restrict__ cursor, int* __restrict__ csr_src,
                              float* __restrict__ csr_norm) {
    int e = blockIdx.x * blockDim.x + threadIdx.x;
    if (e >= N_EDGES) return;
    int s = ei[e];
    int d = ei[N_EDGES + e];
    int pos = offs[d] + atomicAdd(&cursor[d], 1);
    csr_src[pos]  = s;
    csr_norm[pos] = dinv[s] * ew[e] * dinv[d];
}

// ---------------- SGEMM: C[M,256] = A[M,K] * W[256,K]^T ----------------
// 128x64 tile, 256 threads, 8x4 microtile, BK=8 (168 and 256 both divisible by 8)

#define BM 128
#define BN 64
#define BK 8

__global__ __launch_bounds__(256) void sgemm_nt(const float* __restrict__ A,
                                                const float* __restrict__ W,
                                                float* __restrict__ C,
                                                int M, int K) {
    __shared__ float As[BK][BM];
    __shared__ float Ws[BK][BN];
    int bm = blockIdx.x * BM;
    int bn = blockIdx.y * BN;
    int tid = threadIdx.x;
    int tx = tid & 15;       // 0..15 -> N (4 cols each)
    int ty = tid >> 4;       // 0..15 -> M (8 rows each)
    float acc[8][4] = {};

    for (int k0 = 0; k0 < K; k0 += BK) {
        // stage A tile: 128 rows x 8 k = 1024 floats, one float4 per thread
        {
            int r = tid >> 1;            // 0..127
            int c = (tid & 1) * 4;       // 0 or 4
            int gm = bm + r;
            float4 a = make_float4(0.f, 0.f, 0.f, 0.f);
            if (gm < M) a = *(const float4*)&A[(size_t)gm * K + k0 + c];
            As[c + 0][r] = a.x; As[c + 1][r] = a.y;
            As[c + 2][r] = a.z; As[c + 3][r] = a.w;
        }
        // stage W tile: 64 rows x 8 k = 512 floats, threads 0..127
        if (tid < 128) {
            int r = tid >> 1;            // 0..63
            int c = (tid & 1) * 4;
            float4 w = *(const float4*)&W[(size_t)(bn + r) * K + k0 + c];
            Ws[c + 0][r] = w.x; Ws[c + 1][r] = w.y;
            Ws[c + 2][r] = w.z; Ws[c + 3][r] = w.w;
        }
        __syncthreads();

        #pragma unroll
        for (int k = 0; k < BK; ++k) {
            float4 a0 = *(const float4*)&As[k][ty * 8];
            float4 a1 = *(const float4*)&As[k][ty * 8 + 4];
            float4 b  = *(const float4*)&Ws[k][tx * 4];
            float am[8] = {a0.x, a0.y, a0.z, a0.w, a1.x, a1.y, a1.z, a1.w};
            float bb[4] = {b.x, b.y, b.z, b.w};
            #pragma unroll
            for (int i = 0; i < 8; ++i)
                #pragma unroll
                for (int j = 0; j < 4; ++j)
                    acc[i][j] += am[i] * bb[j];
        }
        __syncthreads();
    }

    #pragma unroll
    for (int i = 0; i < 8; ++i) {
        int gm = bm + ty * 8 + i;
        if (gm < M) {
            float4 v = make_float4(acc[i][0], acc[i][1], acc[i][2], acc[i][3]);
            *(float4*)&C[(size_t)gm * HID + bn + tx * 4] = v;
        }
    }
}

// ---------------- aggregation (+self-loop, +bias, ReLU) ----------------
// one WAVE per dst node; 64 lanes x float4 = one 1KB row per load issue

__global__ __launch_bounds__(256) void aggregate4(const float4* __restrict__ xw4,
                                                  const float* __restrict__ dinv,
                                                  const int* __restrict__ offs,
                                                  const int* __restrict__ csr_src,
                                                  const float* __restrict__ csr_norm,
                                                  const float4* __restrict__ bias4,
                                                  float4* __restrict__ out4) {
    int wave = threadIdx.x >> 6;
    int lane = threadIdx.x & 63;
    int n = blockIdx.x * 4 + wave;      // N_NODES % 4 == 0
    float di = dinv[n];
    float sw = di * di;
    float4 v = xw4[(size_t)n * 64 + lane];
    float ax = sw * v.x, ay = sw * v.y, az = sw * v.z, aw = sw * v.w;

    int p0 = offs[n], p1 = offs[n + 1];
    int p = p0;
    for (; p + 2 <= p1; p += 2) {
        int   s0 = csr_src[p];
        int   s1 = csr_src[p + 1];
        float w0 = csr_norm[p];
        float w1 = csr_norm[p + 1];
        float4 r0 = xw4[(size_t)s0 * 64 + lane];
        float4 r1 = xw4[(size_t)s1 * 64 + lane];
        ax += w0 * r0.x + w1 * r1.x;
        ay += w0 * r0.y + w1 * r1.y;
        az += w0 * r0.z + w1 * r1.z;
        aw += w0 * r0.w + w1 * r1.w;
    }
    if (p < p1) {
        int   s0 = csr_src[p];
        float w0 = csr_norm[p];
        float4 r0 = xw4[(size_t)s0 * 64 + lane];
        ax += w0 * r0.x; ay += w0 * r0.y; az += w0 * r0.z; aw += w0 * r0.w;
    }

    float4 b = bias4[lane];
    ax += b.x; ay += b.y; az += b.z; aw += b.w;
    float4 o;
    o.x = ax > 0.f ? ax : 0.f;
    o.y = ay > 0.f ? ay : 0.f;
    o.z = az > 0.f ? az : 0.f;
    o.w = aw > 0.f ? aw : 0.f;
    out4[(size_t)n * 64 + lane] = o;
}

// ---------------- launch ----------------

extern "C" void kernel_launch(void* const* d_in, const int* in_sizes, int n_in,
                              void* d_out, int out_size, void* d_ws, size_t ws_size,
                              hipStream_t stream) {
    const float* x  = (const float*)d_in[0];
    const int*   ei = (const int*)d_in[1];
    const float* ew = (const float*)d_in[2];
    const float* W1 = (const float*)d_in[3];
    const float* b1 = (const float*)d_in[4];
    const float* W2 = (const float*)d_in[5];
    const float* b2 = (const float*)d_in[6];
    float* out = (float*)d_out;

    char* ws = (char*)d_ws;
    float* deg      = (float*)(ws);                         // 20000 f32  (becomes dinv)
    int*   counts   = (int*)(ws + 80000);                   // 20000 i32
    int*   cursor   = (int*)(ws + 160000);                  // 20000 i32
    int*   offs     = (int*)(ws + 240000);                  // 20001 i32 (pad to 80016)
    int*   csr_src  = (int*)(ws + 320016);                  // 320000 i32
    float* csr_norm = (float*)(ws + 1600016);               // 320000 f32
    float* xw       = (float*)(ws + 2880016);               // 20000x256 f32
    float* h1       = (float*)(ws + 23360016);              // 20000x256 f32

    hipMemsetAsync(d_ws, 0, 240000, stream);

    const int TB = 256;
    edge_count_deg<<<(N_EDGES + TB - 1) / TB, TB, 0, stream>>>(ei, ew, deg, counts);
    finalize_dinv<<<(N_NODES + TB - 1) / TB, TB, 0, stream>>>(deg);
    scan_counts<<<1, 1024, 0, stream>>>(counts, offs, N_NODES);
    scatter_edges<<<(N_EDGES + TB - 1) / TB, TB, 0, stream>>>(ei, ew, deg, offs, cursor,
                                                              csr_src, csr_norm);

    dim3 g1((N_NODES + BM - 1) / BM, HID / BN);
    // layer 1
    sgemm_nt<<<g1, 256, 0, stream>>>(x, W1, xw, N_NODES, IN_F);
    aggregate4<<<N_NODES / 4, 256, 0, stream>>>((const float4*)xw, deg, offs, csr_src,
                                                csr_norm, (const float4*)b1, (float4*)h1);
    // layer 2
    sgemm_nt<<<g1, 256, 0, stream>>>(h1, W2, xw, N_NODES, HID);
    aggregate4<<<N_NODES / 4, 256, 0, stream>>>((const float4*)xw, deg, offs, csr_src,
                                                csr_norm, (const float4*)b2, (float4*)out);
}